// Round 19
// baseline (569.986 us; speedup 1.0000x reference)
//
#include <hip/hip_runtime.h>
#include <hip/hip_bf16.h>
#include <cstdint>

#define NSEQ  2048
#define BSZ   2
#define NTOK  4096          // B*N
#define EDIM  1024
#define NEXP  16
#define CAPC  160
#define HFF_R 2730
#define HFF_P 2752          // padded to multiple of 64

typedef __bf16 bf16_t;
typedef __bf16 bf16x8 __attribute__((ext_vector_type(8)));
typedef __bf16 bf16x4 __attribute__((ext_vector_type(4)));
typedef float  f32x4  __attribute__((ext_vector_type(4)));
typedef unsigned int uint32;

__device__ inline bf16x8 zero8() {
    bf16x8 v;
#pragma unroll
    for (int i = 0; i < 8; i++) v[i] = (bf16_t)0.f;
    return v;
}
__device__ inline bf16x8 pack8(float4 a, float4 b) {
    bf16x8 v;
    v[0]=(bf16_t)a.x; v[1]=(bf16_t)a.y; v[2]=(bf16_t)a.z; v[3]=(bf16_t)a.w;
    v[4]=(bf16_t)b.x; v[5]=(bf16_t)b.y; v[6]=(bf16_t)b.z; v[7]=(bf16_t)b.w;
    return v;
}
struct hl_t { bf16_t h, l; };
__device__ inline hl_t split1(float f) {
    hl_t r;
    r.h = (bf16_t)f;
    r.l = (bf16_t)(f - (float)r.h);
    return r;
}

// ---------------------------------------------------------------------------
// Elementwise f32 -> (hi, lo) bf16 split. 4 elems/thread.
// ---------------------------------------------------------------------------
__global__ __launch_bounds__(256) void split_kernel(const float* __restrict__ src,
                                                    bf16_t* __restrict__ hi,
                                                    bf16_t* __restrict__ lo, int n)
{
    int i = (blockIdx.x * 256 + threadIdx.x) * 4;
    if (i >= n) return;
    float4 v = *(const float4*)(src + i);
    hl_t a = split1(v.x), b = split1(v.y), c = split1(v.z), d = split1(v.w);
    bf16x4 h, l;
    h[0] = a.h; h[1] = b.h; h[2] = c.h; h[3] = d.h;
    l[0] = a.l; l[1] = b.l; l[2] = c.l; l[3] = d.l;
    *(bf16x4*)(hi + i) = h;
    *(bf16x4*)(lo + i) = l;
}

// ---------------------------------------------------------------------------
// Pre-split NT GEMM. BM=BN=128, BK=32, 4 waves 2x2, reg-staged prefetch.
// ---------------------------------------------------------------------------
template <int EPI, int C_SPLIT>
__global__ __launch_bounds__(256) void gemm_ps(
    const bf16_t* __restrict__ Ah_, const bf16_t* __restrict__ Al_,
    const bf16_t* __restrict__ Bh_, const bf16_t* __restrict__ Bl_,
    const float* __restrict__ bias, const float* __restrict__ resid,
    bf16_t* __restrict__ Chi, bf16_t* __restrict__ Clo, float* __restrict__ Cf,
    int M, int N, int K, int scale_cut, float scale_val)
{
    __shared__ __align__(16) bf16_t Ah[128 * 40], Al[128 * 40];
    __shared__ __align__(16) bf16_t Bh[128 * 40], Bl[128 * 40];
    const int t = threadIdx.x;
    const int m0 = blockIdx.y * 128, n0 = blockIdx.x * 128;
    const int lane = t & 63, l15 = lane & 15, lg = lane >> 4;
    const int wid = t >> 6, wm = wid >> 1, wn = wid & 1;
    const int srow = t >> 1, skc = (t & 1) * 16;

    f32x4 acc[4][4];
    const f32x4 zf = {0.f, 0.f, 0.f, 0.f};
#pragma unroll
    for (int i = 0; i < 4; i++)
#pragma unroll
        for (int j = 0; j < 4; j++) acc[i][j] = zf;

    bf16x8 sah0, sah1, sal0, sal1, sbh0, sbh1, sbl0, sbl1;
    auto LOADAB = [&](int k0) {
        long aoff = (long)(m0 + srow) * K + k0 + skc;
        sah0 = *(const bf16x8*)(Ah_ + aoff); sah1 = *(const bf16x8*)(Ah_ + aoff + 8);
        sal0 = *(const bf16x8*)(Al_ + aoff); sal1 = *(const bf16x8*)(Al_ + aoff + 8);
        long boff = (long)(n0 + srow) * K + k0 + skc;
        sbh0 = *(const bf16x8*)(Bh_ + boff); sbh1 = *(const bf16x8*)(Bh_ + boff + 8);
        sbl0 = *(const bf16x8*)(Bl_ + boff); sbl1 = *(const bf16x8*)(Bl_ + boff + 8);
    };
    auto WRITEAB = [&]() {
        *(bf16x8*)&Ah[srow * 40 + skc] = sah0; *(bf16x8*)&Ah[srow * 40 + skc + 8] = sah1;
        *(bf16x8*)&Al[srow * 40 + skc] = sal0; *(bf16x8*)&Al[srow * 40 + skc + 8] = sal1;
        *(bf16x8*)&Bh[srow * 40 + skc] = sbh0; *(bf16x8*)&Bh[srow * 40 + skc + 8] = sbh1;
        *(bf16x8*)&Bl[srow * 40 + skc] = sbl0; *(bf16x8*)&Bl[srow * 40 + skc + 8] = sbl1;
    };

    LOADAB(0);
    for (int k0 = 0; k0 < K; k0 += 32) {
        WRITEAB();
        __syncthreads();
        if (k0 + 32 < K) LOADAB(k0 + 32);
        bf16x8 amh[4], aml[4], bnh[4], bnl[4];
#pragma unroll
        for (int i = 0; i < 4; i++) {
            int base = (wm * 64 + i * 16 + l15) * 40 + lg * 8;
            amh[i] = *(const bf16x8*)&Ah[base];
            aml[i] = *(const bf16x8*)&Al[base];
        }
#pragma unroll
        for (int j = 0; j < 4; j++) {
            int base = (wn * 64 + j * 16 + l15) * 40 + lg * 8;
            bnh[j] = *(const bf16x8*)&Bh[base];
            bnl[j] = *(const bf16x8*)&Bl[base];
        }
        __builtin_amdgcn_s_setprio(1);
#pragma unroll
        for (int i = 0; i < 4; i++)
#pragma unroll
            for (int j = 0; j < 4; j++) {
                acc[i][j] = __builtin_amdgcn_mfma_f32_16x16x32_bf16(amh[i], bnh[j], acc[i][j], 0, 0, 0);
                acc[i][j] = __builtin_amdgcn_mfma_f32_16x16x32_bf16(amh[i], bnl[j], acc[i][j], 0, 0, 0);
                acc[i][j] = __builtin_amdgcn_mfma_f32_16x16x32_bf16(aml[i], bnh[j], acc[i][j], 0, 0, 0);
            }
        __builtin_amdgcn_s_setprio(0);
        __syncthreads();
    }

#pragma unroll
    for (int i = 0; i < 4; i++) {
        int mgb = m0 + wm * 64 + i * 16 + lg * 4;
#pragma unroll
        for (int j = 0; j < 4; j++) {
            int ng = n0 + wn * 64 + j * 16 + l15;
            float bval = bias[ng];
#pragma unroll
            for (int r = 0; r < 4; r++) {
                int mg = mgb + r;
                float val = acc[i][j][r] + bval;
                if (scale_cut > 0 && ng < scale_cut) val *= scale_val;
                if (EPI == 2) val += resid[(long)mg * N + ng];
                long idx = (long)mg * N + ng;
                if (C_SPLIT) {
                    bf16_t hi = (bf16_t)val;
                    Chi[idx] = hi;
                    Clo[idx] = (bf16_t)(val - (float)hi);
                } else {
                    Cf[idx] = val;
                }
            }
        }
    }
}

// ---------------------------------------------------------------------------
// Expert FFN GEMM (round-13, passing).
// ---------------------------------------------------------------------------
template <int EPI, int C_BF16>
__global__ __launch_bounds__(256) void gemm_ffn(
    const bf16_t* __restrict__ Av, const float* __restrict__ Bw,
    const float* __restrict__ bias, void* __restrict__ Cv,
    int N, int Nwr, int KA, int KB,
    long sAe, long sBe, long sBiasE, long sCe, int ldc)
{
    __shared__ __align__(16) bf16_t Alds[320 * 72];
    __shared__ __align__(16) bf16_t Blds[64 * 72];
    const int id = blockIdx.x;
    const int e = id & 15, nt = id >> 4;
    const int n0 = nt * 64;
    const int t = threadIdx.x;
    const int lane = t & 63, l15 = lane & 15, lg = lane >> 4;
    const int wid = t >> 6, wm = wid >> 1, wn = wid & 1;
    const int srow = t >> 2, scol = (t & 3) * 16;

    f32x4 acc[10][2];
    const f32x4 zf = {0.f, 0.f, 0.f, 0.f};
#pragma unroll
    for (int i = 0; i < 10; i++)
#pragma unroll
        for (int j = 0; j < 2; j++) acc[i][j] = zf;

    bf16x8 sa[5][2];
    float4 sb0, sb1, sb2, sb3;
    const float4 zf4 = {0.f, 0.f, 0.f, 0.f};
    auto LOADA = [&](int k0) {
        const bf16_t* abase = Av + (long)e * sAe + k0 + scol;
#pragma unroll
        for (int p = 0; p < 5; p++) {
            const bf16_t* ap = abase + (long)(srow + 64 * p) * KA;
            sa[p][0] = *(const bf16x8*)ap;
            sa[p][1] = *(const bf16x8*)(ap + 8);
        }
    };
    auto LOADB = [&](int k0) {
        int ng = n0 + srow;
        if (ng < N) {
            const float* bp = Bw + (long)e * sBe + (long)ng * KB + k0 + scol;
            if (k0 + 64 <= KB) {
                sb0 = *(const float4*)bp;       sb1 = *(const float4*)(bp + 4);
                sb2 = *(const float4*)(bp + 8); sb3 = *(const float4*)(bp + 12);
            } else {
                float v[16];
#pragma unroll
                for (int i = 0; i < 16; i++) {
                    int kk = k0 + scol + i;
                    v[i] = (kk < KB) ? bp[i] : 0.f;
                }
                sb0 = *(float4*)&v[0];  sb1 = *(float4*)&v[4];
                sb2 = *(float4*)&v[8];  sb3 = *(float4*)&v[12];
            }
        } else {
            sb0 = zf4; sb1 = zf4; sb2 = zf4; sb3 = zf4;
        }
    };
    auto WRITEAB = [&]() {
#pragma unroll
        for (int p = 0; p < 5; p++) {
            *(bf16x8*)&Alds[(srow + 64 * p) * 72 + scol]     = sa[p][0];
            *(bf16x8*)&Alds[(srow + 64 * p) * 72 + scol + 8] = sa[p][1];
        }
        *(bf16x8*)&Blds[srow * 72 + scol]     = pack8(sb0, sb1);
        *(bf16x8*)&Blds[srow * 72 + scol + 8] = pack8(sb2, sb3);
    };

    LOADA(0); LOADB(0);
    for (int k0 = 0; k0 < KA; k0 += 64) {
        WRITEAB();
        __syncthreads();
        if (k0 + 64 < KA) { LOADA(k0 + 64); LOADB(k0 + 64); }
#pragma unroll
        for (int ks = 0; ks < 2; ks++) {
            bf16x8 bn[2];
#pragma unroll
            for (int j = 0; j < 2; j++)
                bn[j] = *(const bf16x8*)&Blds[(wn * 32 + j * 16 + l15) * 72 + ks * 32 + lg * 8];
            bf16x8 am[10];
#pragma unroll
            for (int i = 0; i < 10; i++)
                am[i] = *(const bf16x8*)&Alds[(wm * 160 + i * 16 + l15) * 72 + ks * 32 + lg * 8];
            __builtin_amdgcn_s_setprio(1);
#pragma unroll
            for (int i = 0; i < 10; i++)
#pragma unroll
                for (int j = 0; j < 2; j++)
                    acc[i][j] = __builtin_amdgcn_mfma_f32_16x16x32_bf16(am[i], bn[j], acc[i][j], 0, 0, 0);
            __builtin_amdgcn_s_setprio(0);
        }
        __syncthreads();
    }

    const float* biasp = bias + (long)e * sBiasE;
#pragma unroll
    for (int i = 0; i < 10; i++) {
        int mgb = wm * 160 + i * 16 + lg * 4;
#pragma unroll
        for (int j = 0; j < 2; j++) {
            int ng = n0 + wn * 32 + j * 16 + l15;
            if (ng < Nwr) {
                float bval = (ng < N) ? biasp[ng] : 0.f;
#pragma unroll
                for (int r = 0; r < 4; r++) {
                    int mg = mgb + r;
                    float val = acc[i][j][r] + bval;
                    if (EPI == 1) val = (val >= 0.f) ? val : 0.01f * val;
                    if (ng >= N) val = 0.f;
                    long cidx = (long)e * sCe + (long)mg * ldc + ng;
                    if (C_BF16) ((bf16_t*)Cv)[cidx] = (bf16_t)val;
                    else        ((float*)Cv)[cidx] = val;
                }
            }
        }
    }
}

// ---------------------------------------------------------------------------
// Split-precision flash attention (round-15 4-wave version: best measured,
// 143 us). 512 blocks x 256 threads; 4 waves x 2 row-groups = 128 q rows.
// Epilogue writes O as hi/lo bf16 for pre-split out_proj.
// ---------------------------------------------------------------------------
__global__ __launch_bounds__(256) void attn_split(const bf16_t* __restrict__ qh,
                                                  const bf16_t* __restrict__ ql,
                                                  bf16_t* __restrict__ oh,
                                                  bf16_t* __restrict__ ol)
{
    __shared__ __align__(16) bf16_t KhS[64 * 72], KlS[64 * 72];
    __shared__ __align__(16) bf16_t VhS[64 * 72], VlS[64 * 72];   // transposed [d][key]
    __shared__ __align__(16) bf16_t PhS[4][2][16 * 72], PlS[4][2][16 * 72];

    const int id = blockIdx.x;
    const int x  = id & 7;
    const int s  = id >> 3;
    const int b  = s >> 5;
    const int s5 = s & 31;
    const int qraw = s5 & 15;
    const int h  = x + 8 * (s5 >> 4);
    const int qt = b ? (15 - qraw) : qraw;
    const int nkb = 2 * qt + 2;

    const int t = threadIdx.x, wid = t >> 6, lane = t & 63, l15 = lane & 15, lg = lane >> 4;
    const int krow = t >> 2, kdc = (t & 3) * 16;
    const int vk = t & 63, vdg = (t >> 6) * 16;
    const long kvb = (long)(b * NSEQ) * 3072 + 1024 + h * 64;
    const f32x4 zf = {0.f, 0.f, 0.f, 0.f};

    const long qo0 = (long)(b * NSEQ + qt * 128 + wid * 16 + l15) * 3072 + h * 64 + lg * 8;
    const long qo1 = qo0 + (long)64 * 3072;
    bf16x8 q0h0 = *(const bf16x8*)(qh + qo0), q0h1 = *(const bf16x8*)(qh + qo0 + 32);
    bf16x8 q0l0 = *(const bf16x8*)(ql + qo0), q0l1 = *(const bf16x8*)(ql + qo0 + 32);
    bf16x8 q1h0 = *(const bf16x8*)(qh + qo1), q1h1 = *(const bf16x8*)(qh + qo1 + 32);
    bf16x8 q1l0 = *(const bf16x8*)(ql + qo1), q1l1 = *(const bf16x8*)(ql + qo1 + 32);

    f32x4 O0[4], O1[4];
    float m0r[4], l0r[4], m1r[4], l1r[4];
#pragma unroll
    for (int r = 0; r < 4; r++) {
        O0[r] = zf; O1[r] = zf;
        m0r[r] = -1e30f; l0r[r] = 0.f; m1r[r] = -1e30f; l1r[r] = 0.f;
    }

    bf16x8 skh0, skh1, skl0, skl1, svh0, svh1, svl0, svl1;
    auto LOADKV = [&](int kb) {
        long ko = kvb + (long)(kb * 64 + krow) * 3072 + kdc;
        skh0 = *(const bf16x8*)(qh + ko); skh1 = *(const bf16x8*)(qh + ko + 8);
        skl0 = *(const bf16x8*)(ql + ko); skl1 = *(const bf16x8*)(ql + ko + 8);
        long vo = kvb + 1024 + (long)(kb * 64 + vk) * 3072 + vdg;
        svh0 = *(const bf16x8*)(qh + vo); svh1 = *(const bf16x8*)(qh + vo + 8);
        svl0 = *(const bf16x8*)(ql + vo); svl1 = *(const bf16x8*)(ql + vo + 8);
    };
    auto WRITEKV = [&]() {
        *(bf16x8*)&KhS[krow * 72 + kdc]     = skh0;
        *(bf16x8*)&KhS[krow * 72 + kdc + 8] = skh1;
        *(bf16x8*)&KlS[krow * 72 + kdc]     = skl0;
        *(bf16x8*)&KlS[krow * 72 + kdc + 8] = skl1;
#pragma unroll
        for (int i = 0; i < 8; i++) {
            VhS[(vdg + i) * 72 + vk]     = svh0[i];
            VhS[(vdg + 8 + i) * 72 + vk] = svh1[i];
            VlS[(vdg + i) * 72 + vk]     = svl0[i];
            VlS[(vdg + 8 + i) * 72 + vk] = svl1[i];
        }
    };

    LOADKV(0);
    for (int kb = 0; kb < nkb; kb++) {
        __syncthreads();
        WRITEKV();
        __syncthreads();
        if (kb + 1 < nkb) LOADKV(kb + 1);
        const bool g0a = (kb < nkb - 1);
        f32x4 s0[4], s1[4];
        __builtin_amdgcn_s_setprio(1);
#pragma unroll
        for (int ks = 0; ks < 4; ks++) {
            int base = (ks * 16 + l15) * 72 + lg * 8;
            bf16x8 kh0 = *(const bf16x8*)&KhS[base];
            bf16x8 kh1 = *(const bf16x8*)&KhS[base + 32];
            bf16x8 kl0 = *(const bf16x8*)&KlS[base];
            bf16x8 kl1 = *(const bf16x8*)&KlS[base + 32];
            f32x4 a = zf;
            a = __builtin_amdgcn_mfma_f32_16x16x32_bf16(q1h0, kh0, a, 0, 0, 0);
            a = __builtin_amdgcn_mfma_f32_16x16x32_bf16(q1h1, kh1, a, 0, 0, 0);
            a = __builtin_amdgcn_mfma_f32_16x16x32_bf16(q1h0, kl0, a, 0, 0, 0);
            a = __builtin_amdgcn_mfma_f32_16x16x32_bf16(q1h1, kl1, a, 0, 0, 0);
            a = __builtin_amdgcn_mfma_f32_16x16x32_bf16(q1l0, kh0, a, 0, 0, 0);
            a = __builtin_amdgcn_mfma_f32_16x16x32_bf16(q1l1, kh1, a, 0, 0, 0);
            s1[ks] = a;
            f32x4 c = zf;
            if (g0a) {
                c = __builtin_amdgcn_mfma_f32_16x16x32_bf16(q0h0, kh0, c, 0, 0, 0);
                c = __builtin_amdgcn_mfma_f32_16x16x32_bf16(q0h1, kh1, c, 0, 0, 0);
                c = __builtin_amdgcn_mfma_f32_16x16x32_bf16(q0h0, kl0, c, 0, 0, 0);
                c = __builtin_amdgcn_mfma_f32_16x16x32_bf16(q0h1, kl1, c, 0, 0, 0);
                c = __builtin_amdgcn_mfma_f32_16x16x32_bf16(q0l0, kh0, c, 0, 0, 0);
                c = __builtin_amdgcn_mfma_f32_16x16x32_bf16(q0l1, kh1, c, 0, 0, 0);
            }
            s0[ks] = c;
        }
        __builtin_amdgcn_s_setprio(0);
        {
            float alpha[4];
#pragma unroll
            for (int r = 0; r < 4; r++) {
                float mt = fmaxf(fmaxf(s1[0][r], s1[1][r]), fmaxf(s1[2][r], s1[3][r]));
#pragma unroll
                for (int m = 1; m < 16; m <<= 1) mt = fmaxf(mt, __shfl_xor(mt, m));
                float mn = fmaxf(m1r[r], mt);
                alpha[r] = __expf(m1r[r] - mn);
                m1r[r] = mn;
            }
            float ladd[4] = {0.f, 0.f, 0.f, 0.f};
#pragma unroll
            for (int ks = 0; ks < 4; ks++)
#pragma unroll
                for (int r = 0; r < 4; r++) {
                    float p = __expf(s1[ks][r] - m1r[r]);
                    s1[ks][r] = p;
                    ladd[r] += p;
                }
#pragma unroll
            for (int r = 0; r < 4; r++) {
#pragma unroll
                for (int m = 1; m < 16; m <<= 1) ladd[r] += __shfl_xor(ladd[r], m);
                l1r[r] = l1r[r] * alpha[r] + ladd[r];
            }
#pragma unroll
            for (int sb = 0; sb < 4; sb++)
#pragma unroll
                for (int r = 0; r < 4; r++) O1[sb][r] *= alpha[r];
            bf16_t* pwh = &PhS[wid][1][0];
            bf16_t* pwl = &PlS[wid][1][0];
#pragma unroll
            for (int ks = 0; ks < 4; ks++)
#pragma unroll
                for (int r = 0; r < 4; r++) {
                    hl_t pv = split1(s1[ks][r]);
                    pwh[(lg * 4 + r) * 72 + ks * 16 + l15] = pv.h;
                    pwl[(lg * 4 + r) * 72 + ks * 16 + l15] = pv.l;
                }
        }
        if (g0a) {
            float alpha[4];
#pragma unroll
            for (int r = 0; r < 4; r++) {
                float mt = fmaxf(fmaxf(s0[0][r], s0[1][r]), fmaxf(s0[2][r], s0[3][r]));
#pragma unroll
                for (int m = 1; m < 16; m <<= 1) mt = fmaxf(mt, __shfl_xor(mt, m));
                float mn = fmaxf(m0r[r], mt);
                alpha[r] = __expf(m0r[r] - mn);
                m0r[r] = mn;
            }
            float ladd[4] = {0.f, 0.f, 0.f, 0.f};
#pragma unroll
            for (int ks = 0; ks < 4; ks++)
#pragma unroll
                for (int r = 0; r < 4; r++) {
                    float p = __expf(s0[ks][r] - m0r[r]);
                    s0[ks][r] = p;
                    ladd[r] += p;
                }
#pragma unroll
            for (int r = 0; r < 4; r++) {
#pragma unroll
                for (int m = 1; m < 16; m <<= 1) ladd[r] += __shfl_xor(ladd[r], m);
                l0r[r] = l0r[r] * alpha[r] + ladd[r];
            }
#pragma unroll
            for (int sb = 0; sb < 4; sb++)
#pragma unroll
                for (int r = 0; r < 4; r++) O0[sb][r] *= alpha[r];
            bf16_t* pwh = &PhS[wid][0][0];
            bf16_t* pwl = &PlS[wid][0][0];
#pragma unroll
            for (int ks = 0; ks < 4; ks++)
#pragma unroll
                for (int r = 0; r < 4; r++) {
                    hl_t pv = split1(s0[ks][r]);
                    pwh[(lg * 4 + r) * 72 + ks * 16 + l15] = pv.h;
                    pwl[(lg * 4 + r) * 72 + ks * 16 + l15] = pv.l;
                }
        }
        __builtin_amdgcn_s_setprio(1);
#pragma unroll
        for (int kst = 0; kst < 2; kst++) {
            bf16x8 pf1h = *(const bf16x8*)&PhS[wid][1][l15 * 72 + kst * 32 + lg * 8];
            bf16x8 pf1l = *(const bf16x8*)&PlS[wid][1][l15 * 72 + kst * 32 + lg * 8];
            bf16x8 pf0h, pf0l;
            if (g0a) {
                pf0h = *(const bf16x8*)&PhS[wid][0][l15 * 72 + kst * 32 + lg * 8];
                pf0l = *(const bf16x8*)&PlS[wid][0][l15 * 72 + kst * 32 + lg * 8];
            }
#pragma unroll
            for (int sb = 0; sb < 4; sb++) {
                int base = (sb * 16 + l15) * 72 + kst * 32 + lg * 8;
                bf16x8 vfh = *(const bf16x8*)&VhS[base];
                bf16x8 vfl = *(const bf16x8*)&VlS[base];
                O1[sb] = __builtin_amdgcn_mfma_f32_16x16x32_bf16(pf1h, vfh, O1[sb], 0, 0, 0);
                O1[sb] = __builtin_amdgcn_mfma_f32_16x16x32_bf16(pf1h, vfl, O1[sb], 0, 0, 0);
                O1[sb] = __builtin_amdgcn_mfma_f32_16x16x32_bf16(pf1l, vfh, O1[sb], 0, 0, 0);
                if (g0a) {
                    O0[sb] = __builtin_amdgcn_mfma_f32_16x16x32_bf16(pf0h, vfh, O0[sb], 0, 0, 0);
                    O0[sb] = __builtin_amdgcn_mfma_f32_16x16x32_bf16(pf0h, vfl, O0[sb], 0, 0, 0);
                    O0[sb] = __builtin_amdgcn_mfma_f32_16x16x32_bf16(pf0l, vfh, O0[sb], 0, 0, 0);
                }
            }
        }
        __builtin_amdgcn_s_setprio(0);
    }
#pragma unroll
    for (int sb = 0; sb < 4; sb++)
#pragma unroll
        for (int r = 0; r < 4; r++) {
            int qg0 = qt * 128 + wid * 16 + lg * 4 + r;
            int col = h * 64 + sb * 16 + l15;
            long i0 = (long)(b * NSEQ + qg0) * 1024 + col;
            long i1 = (long)(b * NSEQ + qg0 + 64) * 1024 + col;
            hl_t v0 = split1(O0[sb][r] / l0r[r]);
            hl_t v1 = split1(O1[sb][r] / l1r[r]);
            oh[i0] = v0.h; ol[i0] = v0.l;
            oh[i1] = v1.h; ol[i1] = v1.l;
        }
}

// ---------------------------------------------------------------------------
__global__ __launch_bounds__(256) void rmsnorm_kernel(const float* __restrict__ y,
                                                      const float* __restrict__ gamma,
                                                      float* __restrict__ moe)
{
    long base = (long)blockIdx.x * 1024;
    float4 v = ((const float4*)(y + base))[threadIdx.x];
    float ss = v.x * v.x + v.y * v.y + v.z * v.z + v.w * v.w;
#pragma unroll
    for (int m = 32; m; m >>= 1) ss += __shfl_xor(ss, m);
    __shared__ float ls[4];
    if ((threadIdx.x & 63) == 0) ls[threadIdx.x >> 6] = ss;
    __syncthreads();
    float tot = ls[0] + ls[1] + ls[2] + ls[3];
    float sc = 32.0f / fmaxf(sqrtf(tot), 1e-12f);
    float4 g = ((const float4*)gamma)[threadIdx.x];
    float4 ov;
    ov.x = v.x * sc * g.x; ov.y = v.y * sc * g.y; ov.z = v.z * sc * g.z; ov.w = v.w * sc * g.w;
    ((float4*)(moe + base))[threadIdx.x] = ov;
}

// ---------------------------------------------------------------------------
__global__ __launch_bounds__(256) void gating_kernel(
    const float* __restrict__ moe, const float* __restrict__ gw,
    const float* __restrict__ runif, uint32* __restrict__ tokpack,
    float* __restrict__ tokg, float* __restrict__ acc)
{
    const int wid = threadIdx.x >> 6, lane = threadIdx.x & 63;
    const int tk = blockIdx.x * 4 + wid;
    const int b = tk >> 11, n = tk & 2047;
    float xv[16];
    const float4* xr4 = (const float4*)(moe + (long)tk * 1024 + lane * 16);
#pragma unroll
    for (int i = 0; i < 4; i++) {
        float4 v = xr4[i];
        xv[4 * i] = v.x; xv[4 * i + 1] = v.y; xv[4 * i + 2] = v.z; xv[4 * i + 3] = v.w;
    }
    float logit[16];
#pragma unroll
    for (int e = 0; e < 16; e++) {
        const float4* wr4 = (const float4*)(gw + e * 1024 + lane * 16);
        float p = 0.f;
#pragma unroll
        for (int i = 0; i < 4; i++) {
            float4 w = wr4[i];
            p = fmaf(xv[4 * i], w.x, p);     p = fmaf(xv[4 * i + 1], w.y, p);
            p = fmaf(xv[4 * i + 2], w.z, p); p = fmaf(xv[4 * i + 3], w.w, p);
        }
#pragma unroll
        for (int m = 1; m < 64; m <<= 1) p += __shfl_xor(p, m);
        logit[e] = p;
    }
    int e0 = 0; float t0 = logit[0];
#pragma unroll
    for (int e = 1; e < 16; e++) if (logit[e] > t0) { t0 = logit[e]; e0 = e; }
    int e1 = (e0 == 0) ? 1 : 0; float t1 = logit[e1];
#pragma unroll
    for (int e = 0; e < 16; e++) if (e != e0 && logit[e] > t1) { t1 = logit[e]; e1 = e; }
    float g0n = 1.f / (1.f + __expf(t1 - t0));
    float g1n = 1.f / (1.f + __expf(t0 - t1));
    int sr1 = (runif[(long)(BSZ + b) * NSEQ + n] < g1n / 0.2f) ? 1 : 0;
    float mx = t0, sum = 0.f, raw[16];
#pragma unroll
    for (int e = 0; e < 16; e++) { raw[e] = __expf(logit[e] - mx); sum += raw[e]; }
    float inv = 1.f / sum;
    float lse = mx + __logf(sum);
    if (lane == 0) {
        tokpack[tk] = (uint32)e0 | ((uint32)e1 << 4) | ((uint32)sr1 << 8);
        tokg[2 * tk] = g0n; tokg[2 * tk + 1] = g1n;
        atomicAdd(&acc[32 + b * 16 + e0], 1.0f);
        atomicAdd(&acc[64], lse * lse);
    }
    if (lane < 16) atomicAdd(&acc[b * 16 + lane], raw[lane] * inv);
}

// ---------------------------------------------------------------------------
__global__ __launch_bounds__(512) void scan_kernel(const uint32* __restrict__ tokpack,
                                                   uint32* __restrict__ r0,
                                                   uint32* __restrict__ r1,
                                                   int* __restrict__ prev)
{
    const int b = blockIdx.x, t = threadIdx.x;
    const int wv = t >> 6, lane = t & 63;
    uint32 toks[4];
    *(uint4*)toks = ((const uint4*)(tokpack + b * NSEQ))[t];

    uint32 c0[8], c1[8];
#pragma unroll
    for (int j = 0; j < 8; j++) { c0[j] = 0u; c1[j] = 0u; }
#pragma unroll
    for (int i = 0; i < 4; i++) {
        uint32 p = toks[i];
        uint32 e0 = p & 15, e1 = (p >> 4) & 15, sr1 = (p >> 8) & 1;
        uint32 inc0 = 1u << ((e0 & 1) * 16);
        uint32 inc1 = sr1 << ((e1 & 1) * 16);
#pragma unroll
        for (int j = 0; j < 8; j++) {
            c0[j] += ((e0 >> 1) == (uint32)j) ? inc0 : 0u;
            c1[j] += ((e1 >> 1) == (uint32)j) ? inc1 : 0u;
        }
    }
    uint32 i0[8], i1[8];
#pragma unroll
    for (int j = 0; j < 8; j++) { i0[j] = c0[j]; i1[j] = c1[j]; }
#pragma unroll
    for (int off = 1; off < 64; off <<= 1) {
#pragma unroll
        for (int j = 0; j < 8; j++) {
            uint32 u0 = __shfl_up(i0[j], off);
            uint32 u1 = __shfl_up(i1[j], off);
            if (lane >= off) { i0[j] += u0; i1[j] += u1; }
        }
    }
    __shared__ uint32 wsum0[8][8], wsum1[8][8];
    if (lane == 63) {
#pragma unroll
        for (int j = 0; j < 8; j++) { wsum0[wv][j] = i0[j]; wsum1[wv][j] = i1[j]; }
    }
    __syncthreads();
    uint32 b0[8], b1[8];
#pragma unroll
    for (int j = 0; j < 8; j++) {
        uint32 s0 = 0u, s1 = 0u;
#pragma unroll
        for (int w = 0; w < 8; w++) {
            s0 += (w < wv) ? wsum0[w][j] : 0u;
            s1 += (w < wv) ? wsum1[w][j] : 0u;
        }
        b0[j] = s0 + i0[j] - c0[j];
        b1[j] = s1 + i1[j] - c1[j];
    }
    if (t == 0) {
#pragma unroll
        for (int j = 0; j < 8; j++) {
            uint32 tot = 0u;
#pragma unroll
            for (int w = 0; w < 8; w++) tot += wsum0[w][j];
            int tlo = (int)(tot & 0xffffu), thi = (int)(tot >> 16);
            prev[b * 16 + 2 * j]     = tlo < CAPC ? tlo : CAPC;
            prev[b * 16 + 2 * j + 1] = thi < CAPC ? thi : CAPC;
        }
    }
    uint32* rr0 = r0 + b * NSEQ + t * 4;
    uint32* rr1 = r1 + b * NSEQ + t * 4;
#pragma unroll
    for (int i = 0; i < 4; i++) {
        uint32 p = toks[i];
        uint32 e0 = p & 15, e1 = (p >> 4) & 15, sr1 = (p >> 8) & 1;
        uint32 sh0 = (e0 & 1) * 16, sh1 = (e1 & 1) * 16;
        uint32 w0 = 0u, w1 = 0u;
#pragma unroll
        for (int j = 0; j < 8; j++) {
            w0 += ((e0 >> 1) == (uint32)j) ? b0[j] : 0u;
            w1 += ((e1 >> 1) == (uint32)j) ? b1[j] : 0u;
        }
        uint32 s0 = (w0 >> sh0) & 0xffffu;
        uint32 s1v = (w1 >> sh1) & 0xffffu;
        uint32 kept = (s0 < CAPC) ? 1u : 0u;
        rr0[i] = e0 | (kept << 4) | (s0 << 5);
        rr1[i] = e1 | (sr1 << 4) | (s1v << 5);
        uint32 inc0 = 1u << sh0;
        uint32 inc1 = sr1 << sh1;
#pragma unroll
        for (int j = 0; j < 8; j++) {
            b0[j] += ((e0 >> 1) == (uint32)j) ? inc0 : 0u;
            b1[j] += ((e1 >> 1) == (uint32)j) ? inc1 : 0u;
        }
    }
}

// ---------------------------------------------------------------------------
// Fused gather + expert LayerNorm (round-18, passing).
// ---------------------------------------------------------------------------
__global__ __launch_bounds__(256) void gather_ln_kernel(
    const float* __restrict__ moe, const uint32* __restrict__ r0,
    const uint32* __restrict__ r1, const int* __restrict__ prev,
    const float* __restrict__ g, const float* __restrict__ bb,
    bf16_t* __restrict__ eln)
{
    int tk = blockIdx.x, b = tk >> 11;
    float4 v = ((const float4*)(moe + (long)tk * 1024))[threadIdx.x];
    float s = v.x + v.y + v.z + v.w;
    float ss = v.x * v.x + v.y * v.y + v.z * v.z + v.w * v.w;
#pragma unroll
    for (int m = 32; m; m >>= 1) { s += __shfl_xor(s, m); ss += __shfl_xor(ss, m); }
    __shared__ float l1[4], l2[4];
    if ((threadIdx.x & 63) == 0) { l1[threadIdx.x >> 6] = s; l2[threadIdx.x >> 6] = ss; }
    __syncthreads();
    float st = l1[0] + l1[1] + l1[2] + l1[3];
    float sst = l2[0] + l2[1] + l2[2] + l2[3];
    float mu = st * (1.f / 1024.f);
    float var = sst * (1.f / 1024.f) - mu * mu;
    float rstd = rsqrtf(var + 1e-5f);
    int d = threadIdx.x * 4;
    float nx = (v.x - mu) * rstd, ny = (v.y - mu) * rstd;
    float nz = (v.z - mu) * rstd, nw = (v.w - mu) * rstd;

    uint32 a = r0[tk];
    if ((a >> 4) & 1) {
        int e = a & 15;
        long row = ((long)e * 2 + b) * CAPC + (int)(a >> 5);
        float4 gg = *(const float4*)(g + e * 1024 + d);
        float4 bv = *(const float4*)(bb + e * 1024 + d);
        bf16x4 ov;
        ov[0] = (bf16_t)(nx * gg.x + bv.x);
        ov[1] = (bf16_t)(ny * gg.y + bv.y);
        ov[2] = (bf16_t)(nz * gg.z + bv.z);
        ov[3] = (bf16_t)(nw * gg.w + bv.w);
        *(bf16x4*)(eln + row * 1024 + d) = ov;
    }
    uint32 c = r1[tk];
    {
        int e = c & 15, sr1 = (c >> 4) & 1;
        int slot = (int)(c >> 5) + prev[b * 16 + e];
        if (sr1 && slot < CAPC) {
            long row = ((long)e * 2 + b) * CAPC + slot;
            float4 gg = *(const float4*)(g + e * 1024 + d);
            float4 bv = *(const float4*)(bb + e * 1024 + d);
            bf16x4 ov;
            ov[0] = (bf16_t)(nx * gg.x + bv.x);
            ov[1] = (bf16_t)(ny * gg.y + bv.y);
            ov[2] = (bf16_t)(nz * gg.z + bv.z);
            ov[3] = (bf16_t)(nw * gg.w + bv.w);
            *(bf16x4*)(eln + row * 1024 + d) = ov;
        }
    }
}

// ---------------------------------------------------------------------------
__global__ __launch_bounds__(256) void combine_kernel(
    const float* __restrict__ y, const float* __restrict__ eout,
    const uint32* __restrict__ r0, const uint32* __restrict__ r1,
    const float* __restrict__ tokg, const int* __restrict__ prev,
    float* __restrict__ out)
{
    int tk = blockIdx.x, b = tk >> 11;
    uint32 a = r0[tk], c = r1[tk];
    int k0f = (a >> 4) & 1;
    float w0 = k0f ? tokg[2 * tk] : 0.f;
    long row0 = ((long)(a & 15) * 2 + b) * CAPC + (int)(a >> 5);
    int e1 = c & 15;
    int slot1 = (int)(c >> 5) + prev[b * 16 + e1];
    int k1f = (((c >> 4) & 1) && slot1 < CAPC) ? 1 : 0;
    float w1 = k1f ? tokg[2 * tk + 1] : 0.f;
    long row1 = ((long)e1 * 2 + b) * CAPC + slot1;
    int i = threadIdx.x;
    float4 vy = ((const float4*)(y + (long)tk * 1024))[i];
    float4 a0 = {0.f, 0.f, 0.f, 0.f}, a1 = {0.f, 0.f, 0.f, 0.f};
    if (k0f) a0 = ((const float4*)(eout + row0 * 1024))[i];
    if (k1f) a1 = ((const float4*)(eout + row1 * 1024))[i];
    float4 ov;
    ov.x = vy.x + w0 * a0.x + w1 * a1.x;
    ov.y = vy.y + w0 * a0.y + w1 * a1.y;
    ov.z = vy.z + w0 * a0.z + w1 * a1.z;
    ov.w = vy.w + w0 * a0.w + w1 * a1.w;
    ((float4*)(out + (long)tk * 1024))[i] = ov;
}

__global__ void zero_acc_kernel(float* acc)
{
    if (threadIdx.x < 65) acc[threadIdx.x] = 0.f;
}

__global__ void finalize_kernel(const float* __restrict__ acc, float* __restrict__ tail)
{
    int t = threadIdx.x;
    float v = (t < 32) ? acc[t] * acc[32 + t] : 0.f;
#pragma unroll
    for (int m = 1; m < 64; m <<= 1) v += __shfl_xor(v, m);
    if (t == 0) {
        float bal = v * (8.0f / (2048.f * 2048.f));
        float z = acc[64] / 4096.f;
        tail[0] = 0.01f * bal + 0.001f * z;
        tail[1] = bal;
        tail[2] = z;
    }
}

// ---------------------------------------------------------------------------
extern "C" void kernel_launch(void* const* d_in, const int* in_sizes, int n_in,
                              void* d_out, int out_size, void* d_ws, size_t ws_size,
                              hipStream_t stream)
{
    (void)in_sizes; (void)n_in; (void)out_size; (void)ws_size;
    const float* x     = (const float*)d_in[0];
    // d_in[1] = attn_mask: block-causal, computed analytically; never read.
    const float* in_w  = (const float*)d_in[2];
    const float* in_b  = (const float*)d_in[3];
    const float* out_w = (const float*)d_in[4];
    const float* out_b = (const float*)d_in[5];
    const float* rg    = (const float*)d_in[6];
    const float* gw    = (const float*)d_in[7];
    const float* lng   = (const float*)d_in[8];
    const float* lnb   = (const float*)d_in[9];
    const float* w1    = (const float*)d_in[10];
    const float* b1    = (const float*)d_in[11];
    const float* w2    = (const float*)d_in[12];
    const float* b2    = (const float*)d_in[13];
    const float* runif = (const float*)d_in[14];
    float* out = (float*)d_out;

    size_t off = 0;
    char* wsb = (char*)d_ws;
    auto take = [&](size_t bytes) -> char* {
        char* p = wsb + off;
        off += (bytes + 255) & ~(size_t)255;
        return p;
    };
    bf16_t* qkvh = (bf16_t*)take((size_t)NTOK * 3072 * 2);   // 25.2 MB
    bf16_t* qkvl = (bf16_t*)take((size_t)NTOK * 3072 * 2);   // 25.2 MB
    bf16_t* oh   = (bf16_t*)take((size_t)NTOK * 1024 * 2);   // 8.4 MB
    bf16_t* ol   = (bf16_t*)take((size_t)NTOK * 1024 * 2);   // 8.4 MB
    float*  ybuf = (float*)take((size_t)NTOK * 1024 * 4);
    float*  moe  = (float*)take((size_t)NTOK * 1024 * 4);
    bf16_t* eln  = (bf16_t*)take((size_t)NEXP * BSZ * CAPC * 1024 * 2);   // 10.5 MB
    bf16_t* hbuf = (bf16_t*)take((size_t)NEXP * BSZ * CAPC * HFF_P * 2);  // 28.2 MB
    bf16_t* owh  = (bf16_t*)take((size_t)1024 * 1024 * 2);   // 2.1 MB
    bf16_t* owl  = (bf16_t*)take((size_t)1024 * 1024 * 2);   // 2.1 MB
    uint32* tokpack = (uint32*)take(NTOK * 4);
    float*  tokg = (float*)take(NTOK * 8);
    uint32* r0   = (uint32*)take(NTOK * 4);
    uint32* r1   = (uint32*)take(NTOK * 4);
    int*    prev = (int*)take(128);
    float*  acc  = (float*)take(1024);
    // aliases (time-disjoint):
    float*  eoutv = (float*)qkvh;                 // dead after attention
    bf16_t* xh    = eln;                          // eln+hbuf region (38.7 MB),
    bf16_t* xl    = xh + (size_t)NTOK * 1024;     // live only until out_proj;
    bf16_t* iwh   = xl + (size_t)NTOK * 1024;     // eln written much later
    bf16_t* iwl   = iwh + (size_t)3072 * 1024;    // total 29.4 MB <= 38.7

    zero_acc_kernel<<<1, 128, 0, stream>>>(acc);

    // pre-split operands (bitwise-identical to inline split)
    split_kernel<<<dim3(NTOK * 1024 / 1024), 256, 0, stream>>>(x, xh, xl, NTOK * 1024);
    split_kernel<<<dim3(3072 * 1024 / 1024), 256, 0, stream>>>(in_w, iwh, iwl, 3072 * 1024);
    split_kernel<<<dim3(1024 * 1024 / 1024), 256, 0, stream>>>(out_w, owh, owl, 1024 * 1024);

    // QKV = x @ in_proj_w^T + b  -> hi/lo; Q cols pre-scaled 1/8
    gemm_ps<0, 1><<<dim3(24, 32), 256, 0, stream>>>(
        xh, xl, iwh, iwl, in_b, nullptr, qkvh, qkvl, nullptr,
        NTOK, 3072, 1024, 1024, 0.125f);

    attn_split<<<dim3(512), 256, 0, stream>>>(qkvh, qkvl, oh, ol);

    // y = o @ out_proj_w^T + b + x  -> f32
    gemm_ps<2, 0><<<dim3(8, 32), 256, 0, stream>>>(
        oh, ol, owh, owl, out_b, x, nullptr, nullptr, ybuf,
        NTOK, 1024, 1024, 0, 1.0f);

    rmsnorm_kernel<<<NTOK, 256, 0, stream>>>(ybuf, rg, moe);
    gating_kernel<<<NTOK / 4, 256, 0, stream>>>(moe, gw, runif, tokpack, tokg, acc);
    scan_kernel<<<dim3(BSZ), 512, 0, stream>>>(tokpack, r0, r1, prev);
    gather_ln_kernel<<<NTOK, 256, 0, stream>>>(moe, r0, r1, prev, lng, lnb, eln);

    // h = LeakyReLU(LN @ w1^T + b1) -> bf16; e = id&15 (XCD-pinned per expert)
    gemm_ffn<1, 1><<<dim3(43 * 16), 256, 0, stream>>>(
        eln, w1, b1, hbuf, HFF_R, HFF_P, 1024, 1024,
        (long)320 * 1024, (long)HFF_R * 1024, HFF_R, (long)320 * HFF_P, HFF_P);

    // expert_out = h @ w2^T + b2 -> f32
    gemm_ffn<0, 0><<<dim3(16 * 16), 256, 0, stream>>>(
        hbuf, w2, b2, eoutv, 1024, 1024, HFF_P, HFF_R,
        (long)320 * HFF_P, (long)1024 * HFF_R, 1024, (long)320 * 1024, 1024);

    combine_kernel<<<NTOK, 256, 0, stream>>>(ybuf, eoutv, r0, r1, tokg, prev, out);
    finalize_kernel<<<1, 64, 0, stream>>>(acc, out + (size_t)NTOK * 1024);
}

// Round 20
// 559.824 us; speedup vs baseline: 1.0182x; 1.0182x over previous
//
#include <hip/hip_runtime.h>
#include <hip/hip_bf16.h>
#include <cstdint>

#define NSEQ  2048
#define BSZ   2
#define NTOK  4096          // B*N
#define EDIM  1024
#define NEXP  16
#define CAPC  160
#define HFF_R 2730
#define HFF_P 2752          // padded to multiple of 64

typedef __bf16 bf16_t;
typedef __bf16 bf16x8 __attribute__((ext_vector_type(8)));
typedef __bf16 bf16x4 __attribute__((ext_vector_type(4)));
typedef float  f32x4  __attribute__((ext_vector_type(4)));
typedef unsigned int uint32;

__device__ inline bf16x8 zero8() {
    bf16x8 v;
#pragma unroll
    for (int i = 0; i < 8; i++) v[i] = (bf16_t)0.f;
    return v;
}
__device__ inline bf16x8 pack8(float4 a, float4 b) {
    bf16x8 v;
    v[0]=(bf16_t)a.x; v[1]=(bf16_t)a.y; v[2]=(bf16_t)a.z; v[3]=(bf16_t)a.w;
    v[4]=(bf16_t)b.x; v[5]=(bf16_t)b.y; v[6]=(bf16_t)b.z; v[7]=(bf16_t)b.w;
    return v;
}
struct hl_t { bf16_t h, l; };
__device__ inline hl_t split1(float f) {
    hl_t r;
    r.h = (bf16_t)f;
    r.l = (bf16_t)(f - (float)r.h);
    return r;
}

// ---------------------------------------------------------------------------
// Elementwise f32 -> (hi, lo) bf16 split. 4 elems/thread.
// ---------------------------------------------------------------------------
__global__ __launch_bounds__(256) void split_kernel(const float* __restrict__ src,
                                                    bf16_t* __restrict__ hi,
                                                    bf16_t* __restrict__ lo, int n)
{
    int i = (blockIdx.x * 256 + threadIdx.x) * 4;
    if (i >= n) return;
    float4 v = *(const float4*)(src + i);
    hl_t a = split1(v.x), b = split1(v.y), c = split1(v.z), d = split1(v.w);
    bf16x4 h, l;
    h[0] = a.h; h[1] = b.h; h[2] = c.h; h[3] = d.h;
    l[0] = a.l; l[1] = b.l; l[2] = c.l; l[3] = d.l;
    *(bf16x4*)(hi + i) = h;
    *(bf16x4*)(lo + i) = l;
}

// ---------------------------------------------------------------------------
// Pre-split NT GEMM. BM=BN=128, BK=32, 4 waves 2x2, reg-staged prefetch.
// XCD-chunked grid decode: flat grid NB*MB; xcd = id&7 owns n-blocks
// [xcd*CHUNK, (xcd+1)*CHUNK) and iterates all m-blocks -> B-slice stays
// resident in that XCD's L2 (NB must equal 8*CHUNK).
// ---------------------------------------------------------------------------
template <int EPI, int C_SPLIT, int CHUNK>
__global__ __launch_bounds__(256) void gemm_ps(
    const bf16_t* __restrict__ Ah_, const bf16_t* __restrict__ Al_,
    const bf16_t* __restrict__ Bh_, const bf16_t* __restrict__ Bl_,
    const float* __restrict__ bias, const float* __restrict__ resid,
    bf16_t* __restrict__ Chi, bf16_t* __restrict__ Clo, float* __restrict__ Cf,
    int M, int N, int K, int scale_cut, float scale_val)
{
    __shared__ __align__(16) bf16_t Ah[128 * 40], Al[128 * 40];
    __shared__ __align__(16) bf16_t Bh[128 * 40], Bl[128 * 40];
    const int id = blockIdx.x;
    const int xcd = id & 7, loc = id >> 3;
    const int nb = xcd * CHUNK + (loc % CHUNK);
    const int mb = loc / CHUNK;
    const int t = threadIdx.x;
    const int m0 = mb * 128, n0 = nb * 128;
    const int lane = t & 63, l15 = lane & 15, lg = lane >> 4;
    const int wid = t >> 6, wm = wid >> 1, wn = wid & 1;
    const int srow = t >> 1, skc = (t & 1) * 16;

    f32x4 acc[4][4];
    const f32x4 zf = {0.f, 0.f, 0.f, 0.f};
#pragma unroll
    for (int i = 0; i < 4; i++)
#pragma unroll
        for (int j = 0; j < 4; j++) acc[i][j] = zf;

    bf16x8 sah0, sah1, sal0, sal1, sbh0, sbh1, sbl0, sbl1;
    auto LOADAB = [&](int k0) {
        long aoff = (long)(m0 + srow) * K + k0 + skc;
        sah0 = *(const bf16x8*)(Ah_ + aoff); sah1 = *(const bf16x8*)(Ah_ + aoff + 8);
        sal0 = *(const bf16x8*)(Al_ + aoff); sal1 = *(const bf16x8*)(Al_ + aoff + 8);
        long boff = (long)(n0 + srow) * K + k0 + skc;
        sbh0 = *(const bf16x8*)(Bh_ + boff); sbh1 = *(const bf16x8*)(Bh_ + boff + 8);
        sbl0 = *(const bf16x8*)(Bl_ + boff); sbl1 = *(const bf16x8*)(Bl_ + boff + 8);
    };
    auto WRITEAB = [&]() {
        *(bf16x8*)&Ah[srow * 40 + skc] = sah0; *(bf16x8*)&Ah[srow * 40 + skc + 8] = sah1;
        *(bf16x8*)&Al[srow * 40 + skc] = sal0; *(bf16x8*)&Al[srow * 40 + skc + 8] = sal1;
        *(bf16x8*)&Bh[srow * 40 + skc] = sbh0; *(bf16x8*)&Bh[srow * 40 + skc + 8] = sbh1;
        *(bf16x8*)&Bl[srow * 40 + skc] = sbl0; *(bf16x8*)&Bl[srow * 40 + skc + 8] = sbl1;
    };

    LOADAB(0);
    for (int k0 = 0; k0 < K; k0 += 32) {
        WRITEAB();
        __syncthreads();
        if (k0 + 32 < K) LOADAB(k0 + 32);
        bf16x8 amh[4], aml[4], bnh[4], bnl[4];
#pragma unroll
        for (int i = 0; i < 4; i++) {
            int base = (wm * 64 + i * 16 + l15) * 40 + lg * 8;
            amh[i] = *(const bf16x8*)&Ah[base];
            aml[i] = *(const bf16x8*)&Al[base];
        }
#pragma unroll
        for (int j = 0; j < 4; j++) {
            int base = (wn * 64 + j * 16 + l15) * 40 + lg * 8;
            bnh[j] = *(const bf16x8*)&Bh[base];
            bnl[j] = *(const bf16x8*)&Bl[base];
        }
        __builtin_amdgcn_s_setprio(1);
#pragma unroll
        for (int i = 0; i < 4; i++)
#pragma unroll
            for (int j = 0; j < 4; j++) {
                acc[i][j] = __builtin_amdgcn_mfma_f32_16x16x32_bf16(amh[i], bnh[j], acc[i][j], 0, 0, 0);
                acc[i][j] = __builtin_amdgcn_mfma_f32_16x16x32_bf16(amh[i], bnl[j], acc[i][j], 0, 0, 0);
                acc[i][j] = __builtin_amdgcn_mfma_f32_16x16x32_bf16(aml[i], bnh[j], acc[i][j], 0, 0, 0);
            }
        __builtin_amdgcn_s_setprio(0);
        __syncthreads();
    }

#pragma unroll
    for (int i = 0; i < 4; i++) {
        int mgb = m0 + wm * 64 + i * 16 + lg * 4;
#pragma unroll
        for (int j = 0; j < 4; j++) {
            int ng = n0 + wn * 64 + j * 16 + l15;
            float bval = bias[ng];
#pragma unroll
            for (int r = 0; r < 4; r++) {
                int mg = mgb + r;
                float val = acc[i][j][r] + bval;
                if (scale_cut > 0 && ng < scale_cut) val *= scale_val;
                if (EPI == 2) val += resid[(long)mg * N + ng];
                long idx = (long)mg * N + ng;
                if (C_SPLIT) {
                    bf16_t hi = (bf16_t)val;
                    Chi[idx] = hi;
                    Clo[idx] = (bf16_t)(val - (float)hi);
                } else {
                    Cf[idx] = val;
                }
            }
        }
    }
}

// ---------------------------------------------------------------------------
// Expert FFN GEMM (round-13, passing).
// ---------------------------------------------------------------------------
template <int EPI, int C_BF16>
__global__ __launch_bounds__(256) void gemm_ffn(
    const bf16_t* __restrict__ Av, const float* __restrict__ Bw,
    const float* __restrict__ bias, void* __restrict__ Cv,
    int N, int Nwr, int KA, int KB,
    long sAe, long sBe, long sBiasE, long sCe, int ldc)
{
    __shared__ __align__(16) bf16_t Alds[320 * 72];
    __shared__ __align__(16) bf16_t Blds[64 * 72];
    const int id = blockIdx.x;
    const int e = id & 15, nt = id >> 4;
    const int n0 = nt * 64;
    const int t = threadIdx.x;
    const int lane = t & 63, l15 = lane & 15, lg = lane >> 4;
    const int wid = t >> 6, wm = wid >> 1, wn = wid & 1;
    const int srow = t >> 2, scol = (t & 3) * 16;

    f32x4 acc[10][2];
    const f32x4 zf = {0.f, 0.f, 0.f, 0.f};
#pragma unroll
    for (int i = 0; i < 10; i++)
#pragma unroll
        for (int j = 0; j < 2; j++) acc[i][j] = zf;

    bf16x8 sa[5][2];
    float4 sb0, sb1, sb2, sb3;
    const float4 zf4 = {0.f, 0.f, 0.f, 0.f};
    auto LOADA = [&](int k0) {
        const bf16_t* abase = Av + (long)e * sAe + k0 + scol;
#pragma unroll
        for (int p = 0; p < 5; p++) {
            const bf16_t* ap = abase + (long)(srow + 64 * p) * KA;
            sa[p][0] = *(const bf16x8*)ap;
            sa[p][1] = *(const bf16x8*)(ap + 8);
        }
    };
    auto LOADB = [&](int k0) {
        int ng = n0 + srow;
        if (ng < N) {
            const float* bp = Bw + (long)e * sBe + (long)ng * KB + k0 + scol;
            if (k0 + 64 <= KB) {
                sb0 = *(const float4*)bp;       sb1 = *(const float4*)(bp + 4);
                sb2 = *(const float4*)(bp + 8); sb3 = *(const float4*)(bp + 12);
            } else {
                float v[16];
#pragma unroll
                for (int i = 0; i < 16; i++) {
                    int kk = k0 + scol + i;
                    v[i] = (kk < KB) ? bp[i] : 0.f;
                }
                sb0 = *(float4*)&v[0];  sb1 = *(float4*)&v[4];
                sb2 = *(float4*)&v[8];  sb3 = *(float4*)&v[12];
            }
        } else {
            sb0 = zf4; sb1 = zf4; sb2 = zf4; sb3 = zf4;
        }
    };
    auto WRITEAB = [&]() {
#pragma unroll
        for (int p = 0; p < 5; p++) {
            *(bf16x8*)&Alds[(srow + 64 * p) * 72 + scol]     = sa[p][0];
            *(bf16x8*)&Alds[(srow + 64 * p) * 72 + scol + 8] = sa[p][1];
        }
        *(bf16x8*)&Blds[srow * 72 + scol]     = pack8(sb0, sb1);
        *(bf16x8*)&Blds[srow * 72 + scol + 8] = pack8(sb2, sb3);
    };

    LOADA(0); LOADB(0);
    for (int k0 = 0; k0 < KA; k0 += 64) {
        WRITEAB();
        __syncthreads();
        if (k0 + 64 < KA) { LOADA(k0 + 64); LOADB(k0 + 64); }
#pragma unroll
        for (int ks = 0; ks < 2; ks++) {
            bf16x8 bn[2];
#pragma unroll
            for (int j = 0; j < 2; j++)
                bn[j] = *(const bf16x8*)&Blds[(wn * 32 + j * 16 + l15) * 72 + ks * 32 + lg * 8];
            bf16x8 am[10];
#pragma unroll
            for (int i = 0; i < 10; i++)
                am[i] = *(const bf16x8*)&Alds[(wm * 160 + i * 16 + l15) * 72 + ks * 32 + lg * 8];
            __builtin_amdgcn_s_setprio(1);
#pragma unroll
            for (int i = 0; i < 10; i++)
#pragma unroll
                for (int j = 0; j < 2; j++)
                    acc[i][j] = __builtin_amdgcn_mfma_f32_16x16x32_bf16(am[i], bn[j], acc[i][j], 0, 0, 0);
            __builtin_amdgcn_s_setprio(0);
        }
        __syncthreads();
    }

    const float* biasp = bias + (long)e * sBiasE;
#pragma unroll
    for (int i = 0; i < 10; i++) {
        int mgb = wm * 160 + i * 16 + lg * 4;
#pragma unroll
        for (int j = 0; j < 2; j++) {
            int ng = n0 + wn * 32 + j * 16 + l15;
            if (ng < Nwr) {
                float bval = (ng < N) ? biasp[ng] : 0.f;
#pragma unroll
                for (int r = 0; r < 4; r++) {
                    int mg = mgb + r;
                    float val = acc[i][j][r] + bval;
                    if (EPI == 1) val = (val >= 0.f) ? val : 0.01f * val;
                    if (ng >= N) val = 0.f;
                    long cidx = (long)e * sCe + (long)mg * ldc + ng;
                    if (C_BF16) ((bf16_t*)Cv)[cidx] = (bf16_t)val;
                    else        ((float*)Cv)[cidx] = val;
                }
            }
        }
    }
}

// ---------------------------------------------------------------------------
// Split-precision flash attention (round-15 4-wave version: best measured,
// 143 us). 512 blocks x 256 threads; 4 waves x 2 row-groups = 128 q rows.
// ---------------------------------------------------------------------------
__global__ __launch_bounds__(256) void attn_split(const bf16_t* __restrict__ qh,
                                                  const bf16_t* __restrict__ ql,
                                                  bf16_t* __restrict__ oh,
                                                  bf16_t* __restrict__ ol)
{
    __shared__ __align__(16) bf16_t KhS[64 * 72], KlS[64 * 72];
    __shared__ __align__(16) bf16_t VhS[64 * 72], VlS[64 * 72];   // transposed [d][key]
    __shared__ __align__(16) bf16_t PhS[4][2][16 * 72], PlS[4][2][16 * 72];

    const int id = blockIdx.x;
    const int x  = id & 7;
    const int s  = id >> 3;
    const int b  = s >> 5;
    const int s5 = s & 31;
    const int qraw = s5 & 15;
    const int h  = x + 8 * (s5 >> 4);
    const int qt = b ? (15 - qraw) : qraw;
    const int nkb = 2 * qt + 2;

    const int t = threadIdx.x, wid = t >> 6, lane = t & 63, l15 = lane & 15, lg = lane >> 4;
    const int krow = t >> 2, kdc = (t & 3) * 16;
    const int vk = t & 63, vdg = (t >> 6) * 16;
    const long kvb = (long)(b * NSEQ) * 3072 + 1024 + h * 64;
    const f32x4 zf = {0.f, 0.f, 0.f, 0.f};

    const long qo0 = (long)(b * NSEQ + qt * 128 + wid * 16 + l15) * 3072 + h * 64 + lg * 8;
    const long qo1 = qo0 + (long)64 * 3072;
    bf16x8 q0h0 = *(const bf16x8*)(qh + qo0), q0h1 = *(const bf16x8*)(qh + qo0 + 32);
    bf16x8 q0l0 = *(const bf16x8*)(ql + qo0), q0l1 = *(const bf16x8*)(ql + qo0 + 32);
    bf16x8 q1h0 = *(const bf16x8*)(qh + qo1), q1h1 = *(const bf16x8*)(qh + qo1 + 32);
    bf16x8 q1l0 = *(const bf16x8*)(ql + qo1), q1l1 = *(const bf16x8*)(ql + qo1 + 32);

    f32x4 O0[4], O1[4];
    float m0r[4], l0r[4], m1r[4], l1r[4];
#pragma unroll
    for (int r = 0; r < 4; r++) {
        O0[r] = zf; O1[r] = zf;
        m0r[r] = -1e30f; l0r[r] = 0.f; m1r[r] = -1e30f; l1r[r] = 0.f;
    }

    bf16x8 skh0, skh1, skl0, skl1, svh0, svh1, svl0, svl1;
    auto LOADKV = [&](int kb) {
        long ko = kvb + (long)(kb * 64 + krow) * 3072 + kdc;
        skh0 = *(const bf16x8*)(qh + ko); skh1 = *(const bf16x8*)(qh + ko + 8);
        skl0 = *(const bf16x8*)(ql + ko); skl1 = *(const bf16x8*)(ql + ko + 8);
        long vo = kvb + 1024 + (long)(kb * 64 + vk) * 3072 + vdg;
        svh0 = *(const bf16x8*)(qh + vo); svh1 = *(const bf16x8*)(qh + vo + 8);
        svl0 = *(const bf16x8*)(ql + vo); svl1 = *(const bf16x8*)(ql + vo + 8);
    };
    auto WRITEKV = [&]() {
        *(bf16x8*)&KhS[krow * 72 + kdc]     = skh0;
        *(bf16x8*)&KhS[krow * 72 + kdc + 8] = skh1;
        *(bf16x8*)&KlS[krow * 72 + kdc]     = skl0;
        *(bf16x8*)&KlS[krow * 72 + kdc + 8] = skl1;
#pragma unroll
        for (int i = 0; i < 8; i++) {
            VhS[(vdg + i) * 72 + vk]     = svh0[i];
            VhS[(vdg + 8 + i) * 72 + vk] = svh1[i];
            VlS[(vdg + i) * 72 + vk]     = svl0[i];
            VlS[(vdg + 8 + i) * 72 + vk] = svl1[i];
        }
    };

    LOADKV(0);
    for (int kb = 0; kb < nkb; kb++) {
        __syncthreads();
        WRITEKV();
        __syncthreads();
        if (kb + 1 < nkb) LOADKV(kb + 1);
        const bool g0a = (kb < nkb - 1);
        f32x4 s0[4], s1[4];
        __builtin_amdgcn_s_setprio(1);
#pragma unroll
        for (int ks = 0; ks < 4; ks++) {
            int base = (ks * 16 + l15) * 72 + lg * 8;
            bf16x8 kh0 = *(const bf16x8*)&KhS[base];
            bf16x8 kh1 = *(const bf16x8*)&KhS[base + 32];
            bf16x8 kl0 = *(const bf16x8*)&KlS[base];
            bf16x8 kl1 = *(const bf16x8*)&KlS[base + 32];
            f32x4 a = zf;
            a = __builtin_amdgcn_mfma_f32_16x16x32_bf16(q1h0, kh0, a, 0, 0, 0);
            a = __builtin_amdgcn_mfma_f32_16x16x32_bf16(q1h1, kh1, a, 0, 0, 0);
            a = __builtin_amdgcn_mfma_f32_16x16x32_bf16(q1h0, kl0, a, 0, 0, 0);
            a = __builtin_amdgcn_mfma_f32_16x16x32_bf16(q1h1, kl1, a, 0, 0, 0);
            a = __builtin_amdgcn_mfma_f32_16x16x32_bf16(q1l0, kh0, a, 0, 0, 0);
            a = __builtin_amdgcn_mfma_f32_16x16x32_bf16(q1l1, kh1, a, 0, 0, 0);
            s1[ks] = a;
            f32x4 c = zf;
            if (g0a) {
                c = __builtin_amdgcn_mfma_f32_16x16x32_bf16(q0h0, kh0, c, 0, 0, 0);
                c = __builtin_amdgcn_mfma_f32_16x16x32_bf16(q0h1, kh1, c, 0, 0, 0);
                c = __builtin_amdgcn_mfma_f32_16x16x32_bf16(q0h0, kl0, c, 0, 0, 0);
                c = __builtin_amdgcn_mfma_f32_16x16x32_bf16(q0h1, kl1, c, 0, 0, 0);
                c = __builtin_amdgcn_mfma_f32_16x16x32_bf16(q0l0, kh0, c, 0, 0, 0);
                c = __builtin_amdgcn_mfma_f32_16x16x32_bf16(q0l1, kh1, c, 0, 0, 0);
            }
            s0[ks] = c;
        }
        __builtin_amdgcn_s_setprio(0);
        {
            float alpha[4];
#pragma unroll
            for (int r = 0; r < 4; r++) {
                float mt = fmaxf(fmaxf(s1[0][r], s1[1][r]), fmaxf(s1[2][r], s1[3][r]));
#pragma unroll
                for (int m = 1; m < 16; m <<= 1) mt = fmaxf(mt, __shfl_xor(mt, m));
                float mn = fmaxf(m1r[r], mt);
                alpha[r] = __expf(m1r[r] - mn);
                m1r[r] = mn;
            }
            float ladd[4] = {0.f, 0.f, 0.f, 0.f};
#pragma unroll
            for (int ks = 0; ks < 4; ks++)
#pragma unroll
                for (int r = 0; r < 4; r++) {
                    float p = __expf(s1[ks][r] - m1r[r]);
                    s1[ks][r] = p;
                    ladd[r] += p;
                }
#pragma unroll
            for (int r = 0; r < 4; r++) {
#pragma unroll
                for (int m = 1; m < 16; m <<= 1) ladd[r] += __shfl_xor(ladd[r], m);
                l1r[r] = l1r[r] * alpha[r] + ladd[r];
            }
#pragma unroll
            for (int sb = 0; sb < 4; sb++)
#pragma unroll
                for (int r = 0; r < 4; r++) O1[sb][r] *= alpha[r];
            bf16_t* pwh = &PhS[wid][1][0];
            bf16_t* pwl = &PlS[wid][1][0];
#pragma unroll
            for (int ks = 0; ks < 4; ks++)
#pragma unroll
                for (int r = 0; r < 4; r++) {
                    hl_t pv = split1(s1[ks][r]);
                    pwh[(lg * 4 + r) * 72 + ks * 16 + l15] = pv.h;
                    pwl[(lg * 4 + r) * 72 + ks * 16 + l15] = pv.l;
                }
        }
        if (g0a) {
            float alpha[4];
#pragma unroll
            for (int r = 0; r < 4; r++) {
                float mt = fmaxf(fmaxf(s0[0][r], s0[1][r]), fmaxf(s0[2][r], s0[3][r]));
#pragma unroll
                for (int m = 1; m < 16; m <<= 1) mt = fmaxf(mt, __shfl_xor(mt, m));
                float mn = fmaxf(m0r[r], mt);
                alpha[r] = __expf(m0r[r] - mn);
                m0r[r] = mn;
            }
            float ladd[4] = {0.f, 0.f, 0.f, 0.f};
#pragma unroll
            for (int ks = 0; ks < 4; ks++)
#pragma unroll
                for (int r = 0; r < 4; r++) {
                    float p = __expf(s0[ks][r] - m0r[r]);
                    s0[ks][r] = p;
                    ladd[r] += p;
                }
#pragma unroll
            for (int r = 0; r < 4; r++) {
#pragma unroll
                for (int m = 1; m < 16; m <<= 1) ladd[r] += __shfl_xor(ladd[r], m);
                l0r[r] = l0r[r] * alpha[r] + ladd[r];
            }
#pragma unroll
            for (int sb = 0; sb < 4; sb++)
#pragma unroll
                for (int r = 0; r < 4; r++) O0[sb][r] *= alpha[r];
            bf16_t* pwh = &PhS[wid][0][0];
            bf16_t* pwl = &PlS[wid][0][0];
#pragma unroll
            for (int ks = 0; ks < 4; ks++)
#pragma unroll
                for (int r = 0; r < 4; r++) {
                    hl_t pv = split1(s0[ks][r]);
                    pwh[(lg * 4 + r) * 72 + ks * 16 + l15] = pv.h;
                    pwl[(lg * 4 + r) * 72 + ks * 16 + l15] = pv.l;
                }
        }
        __builtin_amdgcn_s_setprio(1);
#pragma unroll
        for (int kst = 0; kst < 2; kst++) {
            bf16x8 pf1h = *(const bf16x8*)&PhS[wid][1][l15 * 72 + kst * 32 + lg * 8];
            bf16x8 pf1l = *(const bf16x8*)&PlS[wid][1][l15 * 72 + kst * 32 + lg * 8];
            bf16x8 pf0h, pf0l;
            if (g0a) {
                pf0h = *(const bf16x8*)&PhS[wid][0][l15 * 72 + kst * 32 + lg * 8];
                pf0l = *(const bf16x8*)&PlS[wid][0][l15 * 72 + kst * 32 + lg * 8];
            }
#pragma unroll
            for (int sb = 0; sb < 4; sb++) {
                int base = (sb * 16 + l15) * 72 + kst * 32 + lg * 8;
                bf16x8 vfh = *(const bf16x8*)&VhS[base];
                bf16x8 vfl = *(const bf16x8*)&VlS[base];
                O1[sb] = __builtin_amdgcn_mfma_f32_16x16x32_bf16(pf1h, vfh, O1[sb], 0, 0, 0);
                O1[sb] = __builtin_amdgcn_mfma_f32_16x16x32_bf16(pf1h, vfl, O1[sb], 0, 0, 0);
                O1[sb] = __builtin_amdgcn_mfma_f32_16x16x32_bf16(pf1l, vfh, O1[sb], 0, 0, 0);
                if (g0a) {
                    O0[sb] = __builtin_amdgcn_mfma_f32_16x16x32_bf16(pf0h, vfh, O0[sb], 0, 0, 0);
                    O0[sb] = __builtin_amdgcn_mfma_f32_16x16x32_bf16(pf0h, vfl, O0[sb], 0, 0, 0);
                    O0[sb] = __builtin_amdgcn_mfma_f32_16x16x32_bf16(pf0l, vfh, O0[sb], 0, 0, 0);
                }
            }
        }
        __builtin_amdgcn_s_setprio(0);
    }
#pragma unroll
    for (int sb = 0; sb < 4; sb++)
#pragma unroll
        for (int r = 0; r < 4; r++) {
            int qg0 = qt * 128 + wid * 16 + lg * 4 + r;
            int col = h * 64 + sb * 16 + l15;
            long i0 = (long)(b * NSEQ + qg0) * 1024 + col;
            long i1 = (long)(b * NSEQ + qg0 + 64) * 1024 + col;
            hl_t v0 = split1(O0[sb][r] / l0r[r]);
            hl_t v1 = split1(O1[sb][r] / l1r[r]);
            oh[i0] = v0.h; ol[i0] = v0.l;
            oh[i1] = v1.h; ol[i1] = v1.l;
        }
}

// ---------------------------------------------------------------------------
__global__ __launch_bounds__(256) void rmsnorm_kernel(const float* __restrict__ y,
                                                      const float* __restrict__ gamma,
                                                      float* __restrict__ moe)
{
    long base = (long)blockIdx.x * 1024;
    float4 v = ((const float4*)(y + base))[threadIdx.x];
    float ss = v.x * v.x + v.y * v.y + v.z * v.z + v.w * v.w;
#pragma unroll
    for (int m = 32; m; m >>= 1) ss += __shfl_xor(ss, m);
    __shared__ float ls[4];
    if ((threadIdx.x & 63) == 0) ls[threadIdx.x >> 6] = ss;
    __syncthreads();
    float tot = ls[0] + ls[1] + ls[2] + ls[3];
    float sc = 32.0f / fmaxf(sqrtf(tot), 1e-12f);
    float4 g = ((const float4*)gamma)[threadIdx.x];
    float4 ov;
    ov.x = v.x * sc * g.x; ov.y = v.y * sc * g.y; ov.z = v.z * sc * g.z; ov.w = v.w * sc * g.w;
    ((float4*)(moe + base))[threadIdx.x] = ov;
}

// ---------------------------------------------------------------------------
__global__ __launch_bounds__(256) void gating_kernel(
    const float* __restrict__ moe, const float* __restrict__ gw,
    const float* __restrict__ runif, uint32* __restrict__ tokpack,
    float* __restrict__ tokg, float* __restrict__ acc)
{
    const int wid = threadIdx.x >> 6, lane = threadIdx.x & 63;
    const int tk = blockIdx.x * 4 + wid;
    const int b = tk >> 11, n = tk & 2047;
    float xv[16];
    const float4* xr4 = (const float4*)(moe + (long)tk * 1024 + lane * 16);
#pragma unroll
    for (int i = 0; i < 4; i++) {
        float4 v = xr4[i];
        xv[4 * i] = v.x; xv[4 * i + 1] = v.y; xv[4 * i + 2] = v.z; xv[4 * i + 3] = v.w;
    }
    float logit[16];
#pragma unroll
    for (int e = 0; e < 16; e++) {
        const float4* wr4 = (const float4*)(gw + e * 1024 + lane * 16);
        float p = 0.f;
#pragma unroll
        for (int i = 0; i < 4; i++) {
            float4 w = wr4[i];
            p = fmaf(xv[4 * i], w.x, p);     p = fmaf(xv[4 * i + 1], w.y, p);
            p = fmaf(xv[4 * i + 2], w.z, p); p = fmaf(xv[4 * i + 3], w.w, p);
        }
#pragma unroll
        for (int m = 1; m < 64; m <<= 1) p += __shfl_xor(p, m);
        logit[e] = p;
    }
    int e0 = 0; float t0 = logit[0];
#pragma unroll
    for (int e = 1; e < 16; e++) if (logit[e] > t0) { t0 = logit[e]; e0 = e; }
    int e1 = (e0 == 0) ? 1 : 0; float t1 = logit[e1];
#pragma unroll
    for (int e = 0; e < 16; e++) if (e != e0 && logit[e] > t1) { t1 = logit[e]; e1 = e; }
    float g0n = 1.f / (1.f + __expf(t1 - t0));
    float g1n = 1.f / (1.f + __expf(t0 - t1));
    int sr1 = (runif[(long)(BSZ + b) * NSEQ + n] < g1n / 0.2f) ? 1 : 0;
    float mx = t0, sum = 0.f, raw[16];
#pragma unroll
    for (int e = 0; e < 16; e++) { raw[e] = __expf(logit[e] - mx); sum += raw[e]; }
    float inv = 1.f / sum;
    float lse = mx + __logf(sum);
    if (lane == 0) {
        tokpack[tk] = (uint32)e0 | ((uint32)e1 << 4) | ((uint32)sr1 << 8);
        tokg[2 * tk] = g0n; tokg[2 * tk + 1] = g1n;
        atomicAdd(&acc[32 + b * 16 + e0], 1.0f);
        atomicAdd(&acc[64], lse * lse);
    }
    if (lane < 16) atomicAdd(&acc[b * 16 + lane], raw[lane] * inv);
}

// ---------------------------------------------------------------------------
__global__ __launch_bounds__(512) void scan_kernel(const uint32* __restrict__ tokpack,
                                                   uint32* __restrict__ r0,
                                                   uint32* __restrict__ r1,
                                                   int* __restrict__ prev)
{
    const int b = blockIdx.x, t = threadIdx.x;
    const int wv = t >> 6, lane = t & 63;
    uint32 toks[4];
    *(uint4*)toks = ((const uint4*)(tokpack + b * NSEQ))[t];

    uint32 c0[8], c1[8];
#pragma unroll
    for (int j = 0; j < 8; j++) { c0[j] = 0u; c1[j] = 0u; }
#pragma unroll
    for (int i = 0; i < 4; i++) {
        uint32 p = toks[i];
        uint32 e0 = p & 15, e1 = (p >> 4) & 15, sr1 = (p >> 8) & 1;
        uint32 inc0 = 1u << ((e0 & 1) * 16);
        uint32 inc1 = sr1 << ((e1 & 1) * 16);
#pragma unroll
        for (int j = 0; j < 8; j++) {
            c0[j] += ((e0 >> 1) == (uint32)j) ? inc0 : 0u;
            c1[j] += ((e1 >> 1) == (uint32)j) ? inc1 : 0u;
        }
    }
    uint32 i0[8], i1[8];
#pragma unroll
    for (int j = 0; j < 8; j++) { i0[j] = c0[j]; i1[j] = c1[j]; }
#pragma unroll
    for (int off = 1; off < 64; off <<= 1) {
#pragma unroll
        for (int j = 0; j < 8; j++) {
            uint32 u0 = __shfl_up(i0[j], off);
            uint32 u1 = __shfl_up(i1[j], off);
            if (lane >= off) { i0[j] += u0; i1[j] += u1; }
        }
    }
    __shared__ uint32 wsum0[8][8], wsum1[8][8];
    if (lane == 63) {
#pragma unroll
        for (int j = 0; j < 8; j++) { wsum0[wv][j] = i0[j]; wsum1[wv][j] = i1[j]; }
    }
    __syncthreads();
    uint32 b0[8], b1[8];
#pragma unroll
    for (int j = 0; j < 8; j++) {
        uint32 s0 = 0u, s1 = 0u;
#pragma unroll
        for (int w = 0; w < 8; w++) {
            s0 += (w < wv) ? wsum0[w][j] : 0u;
            s1 += (w < wv) ? wsum1[w][j] : 0u;
        }
        b0[j] = s0 + i0[j] - c0[j];
        b1[j] = s1 + i1[j] - c1[j];
    }
    if (t == 0) {
#pragma unroll
        for (int j = 0; j < 8; j++) {
            uint32 tot = 0u;
#pragma unroll
            for (int w = 0; w < 8; w++) tot += wsum0[w][j];
            int tlo = (int)(tot & 0xffffu), thi = (int)(tot >> 16);
            prev[b * 16 + 2 * j]     = tlo < CAPC ? tlo : CAPC;
            prev[b * 16 + 2 * j + 1] = thi < CAPC ? thi : CAPC;
        }
    }
    uint32* rr0 = r0 + b * NSEQ + t * 4;
    uint32* rr1 = r1 + b * NSEQ + t * 4;
#pragma unroll
    for (int i = 0; i < 4; i++) {
        uint32 p = toks[i];
        uint32 e0 = p & 15, e1 = (p >> 4) & 15, sr1 = (p >> 8) & 1;
        uint32 sh0 = (e0 & 1) * 16, sh1 = (e1 & 1) * 16;
        uint32 w0 = 0u, w1 = 0u;
#pragma unroll
        for (int j = 0; j < 8; j++) {
            w0 += ((e0 >> 1) == (uint32)j) ? b0[j] : 0u;
            w1 += ((e1 >> 1) == (uint32)j) ? b1[j] : 0u;
        }
        uint32 s0 = (w0 >> sh0) & 0xffffu;
        uint32 s1v = (w1 >> sh1) & 0xffffu;
        uint32 kept = (s0 < CAPC) ? 1u : 0u;
        rr0[i] = e0 | (kept << 4) | (s0 << 5);
        rr1[i] = e1 | (sr1 << 4) | (s1v << 5);
        uint32 inc0 = 1u << sh0;
        uint32 inc1 = sr1 << sh1;
#pragma unroll
        for (int j = 0; j < 8; j++) {
            b0[j] += ((e0 >> 1) == (uint32)j) ? inc0 : 0u;
            b1[j] += ((e1 >> 1) == (uint32)j) ? inc1 : 0u;
        }
    }
}

// ---------------------------------------------------------------------------
// Fused gather + expert LayerNorm (round-18, passing).
// ---------------------------------------------------------------------------
__global__ __launch_bounds__(256) void gather_ln_kernel(
    const float* __restrict__ moe, const uint32* __restrict__ r0,
    const uint32* __restrict__ r1, const int* __restrict__ prev,
    const float* __restrict__ g, const float* __restrict__ bb,
    bf16_t* __restrict__ eln)
{
    int tk = blockIdx.x, b = tk >> 11;
    float4 v = ((const float4*)(moe + (long)tk * 1024))[threadIdx.x];
    float s = v.x + v.y + v.z + v.w;
    float ss = v.x * v.x + v.y * v.y + v.z * v.z + v.w * v.w;
#pragma unroll
    for (int m = 32; m; m >>= 1) { s += __shfl_xor(s, m); ss += __shfl_xor(ss, m); }
    __shared__ float l1[4], l2[4];
    if ((threadIdx.x & 63) == 0) { l1[threadIdx.x >> 6] = s; l2[threadIdx.x >> 6] = ss; }
    __syncthreads();
    float st = l1[0] + l1[1] + l1[2] + l1[3];
    float sst = l2[0] + l2[1] + l2[2] + l2[3];
    float mu = st * (1.f / 1024.f);
    float var = sst * (1.f / 1024.f) - mu * mu;
    float rstd = rsqrtf(var + 1e-5f);
    int d = threadIdx.x * 4;
    float nx = (v.x - mu) * rstd, ny = (v.y - mu) * rstd;
    float nz = (v.z - mu) * rstd, nw = (v.w - mu) * rstd;

    uint32 a = r0[tk];
    if ((a >> 4) & 1) {
        int e = a & 15;
        long row = ((long)e * 2 + b) * CAPC + (int)(a >> 5);
        float4 gg = *(const float4*)(g + e * 1024 + d);
        float4 bv = *(const float4*)(bb + e * 1024 + d);
        bf16x4 ov;
        ov[0] = (bf16_t)(nx * gg.x + bv.x);
        ov[1] = (bf16_t)(ny * gg.y + bv.y);
        ov[2] = (bf16_t)(nz * gg.z + bv.z);
        ov[3] = (bf16_t)(nw * gg.w + bv.w);
        *(bf16x4*)(eln + row * 1024 + d) = ov;
    }
    uint32 c = r1[tk];
    {
        int e = c & 15, sr1 = (c >> 4) & 1;
        int slot = (int)(c >> 5) + prev[b * 16 + e];
        if (sr1 && slot < CAPC) {
            long row = ((long)e * 2 + b) * CAPC + slot;
            float4 gg = *(const float4*)(g + e * 1024 + d);
            float4 bv = *(const float4*)(bb + e * 1024 + d);
            bf16x4 ov;
            ov[0] = (bf16_t)(nx * gg.x + bv.x);
            ov[1] = (bf16_t)(ny * gg.y + bv.y);
            ov[2] = (bf16_t)(nz * gg.z + bv.z);
            ov[3] = (bf16_t)(nw * gg.w + bv.w);
            *(bf16x4*)(eln + row * 1024 + d) = ov;
        }
    }
}

// ---------------------------------------------------------------------------
__global__ __launch_bounds__(256) void combine_kernel(
    const float* __restrict__ y, const float* __restrict__ eout,
    const uint32* __restrict__ r0, const uint32* __restrict__ r1,
    const float* __restrict__ tokg, const int* __restrict__ prev,
    float* __restrict__ out)
{
    int tk = blockIdx.x, b = tk >> 11;
    uint32 a = r0[tk], c = r1[tk];
    int k0f = (a >> 4) & 1;
    float w0 = k0f ? tokg[2 * tk] : 0.f;
    long row0 = ((long)(a & 15) * 2 + b) * CAPC + (int)(a >> 5);
    int e1 = c & 15;
    int slot1 = (int)(c >> 5) + prev[b * 16 + e1];
    int k1f = (((c >> 4) & 1) && slot1 < CAPC) ? 1 : 0;
    float w1 = k1f ? tokg[2 * tk + 1] : 0.f;
    long row1 = ((long)e1 * 2 + b) * CAPC + slot1;
    int i = threadIdx.x;
    float4 vy = ((const float4*)(y + (long)tk * 1024))[i];
    float4 a0 = {0.f, 0.f, 0.f, 0.f}, a1 = {0.f, 0.f, 0.f, 0.f};
    if (k0f) a0 = ((const float4*)(eout + row0 * 1024))[i];
    if (k1f) a1 = ((const float4*)(eout + row1 * 1024))[i];
    float4 ov;
    ov.x = vy.x + w0 * a0.x + w1 * a1.x;
    ov.y = vy.y + w0 * a0.y + w1 * a1.y;
    ov.z = vy.z + w0 * a0.z + w1 * a1.z;
    ov.w = vy.w + w0 * a0.w + w1 * a1.w;
    ((float4*)(out + (long)tk * 1024))[i] = ov;
}

__global__ void zero_acc_kernel(float* acc)
{
    if (threadIdx.x < 65) acc[threadIdx.x] = 0.f;
}

__global__ void finalize_kernel(const float* __restrict__ acc, float* __restrict__ tail)
{
    int t = threadIdx.x;
    float v = (t < 32) ? acc[t] * acc[32 + t] : 0.f;
#pragma unroll
    for (int m = 1; m < 64; m <<= 1) v += __shfl_xor(v, m);
    if (t == 0) {
        float bal = v * (8.0f / (2048.f * 2048.f));
        float z = acc[64] / 4096.f;
        tail[0] = 0.01f * bal + 0.001f * z;
        tail[1] = bal;
        tail[2] = z;
    }
}

// ---------------------------------------------------------------------------
extern "C" void kernel_launch(void* const* d_in, const int* in_sizes, int n_in,
                              void* d_out, int out_size, void* d_ws, size_t ws_size,
                              hipStream_t stream)
{
    (void)in_sizes; (void)n_in; (void)out_size; (void)ws_size;
    const float* x     = (const float*)d_in[0];
    // d_in[1] = attn_mask: block-causal, computed analytically; never read.
    const float* in_w  = (const float*)d_in[2];
    const float* in_b  = (const float*)d_in[3];
    const float* out_w = (const float*)d_in[4];
    const float* out_b = (const float*)d_in[5];
    const float* rg    = (const float*)d_in[6];
    const float* gw    = (const float*)d_in[7];
    const float* lng   = (const float*)d_in[8];
    const float* lnb   = (const float*)d_in[9];
    const float* w1    = (const float*)d_in[10];
    const float* b1    = (const float*)d_in[11];
    const float* w2    = (const float*)d_in[12];
    const float* b2    = (const float*)d_in[13];
    const float* runif = (const float*)d_in[14];
    float* out = (float*)d_out;

    size_t off = 0;
    char* wsb = (char*)d_ws;
    auto take = [&](size_t bytes) -> char* {
        char* p = wsb + off;
        off += (bytes + 255) & ~(size_t)255;
        return p;
    };
    bf16_t* qkvh = (bf16_t*)take((size_t)NTOK * 3072 * 2);   // 25.2 MB
    bf16_t* qkvl = (bf16_t*)take((size_t)NTOK * 3072 * 2);   // 25.2 MB
    bf16_t* oh   = (bf16_t*)take((size_t)NTOK * 1024 * 2);   // 8.4 MB
    bf16_t* ol   = (bf16_t*)take((size_t)NTOK * 1024 * 2);   // 8.4 MB
    float*  ybuf = (float*)take((size_t)NTOK * 1024 * 4);
    float*  moe  = (float*)take((size_t)NTOK * 1024 * 4);
    bf16_t* eln  = (bf16_t*)take((size_t)NEXP * BSZ * CAPC * 1024 * 2);   // 10.5 MB
    bf16_t* hbuf = (bf16_t*)take((size_t)NEXP * BSZ * CAPC * HFF_P * 2);  // 28.2 MB
    bf16_t* owh  = (bf16_t*)take((size_t)1024 * 1024 * 2);   // 2.1 MB
    bf16_t* owl  = (bf16_t*)take((size_t)1024 * 1024 * 2);   // 2.1 MB
    uint32* tokpack = (uint32*)take(NTOK * 4);
    float*  tokg = (float*)take(NTOK * 8);
    uint32* r0   = (uint32*)take(NTOK * 4);
    uint32* r1   = (uint32*)take(NTOK * 4);
    int*    prev = (int*)take(128);
    float*  acc  = (float*)take(1024);
    // aliases (time-disjoint):
    float*  eoutv = (float*)qkvh;                 // dead after attention
    bf16_t* xh    = eln;                          // eln+hbuf region (38.7 MB),
    bf16_t* xl    = xh + (size_t)NTOK * 1024;     // live only until out_proj;
    bf16_t* iwh   = xl + (size_t)NTOK * 1024;     // eln written much later
    bf16_t* iwl   = iwh + (size_t)3072 * 1024;    // total 29.4 MB <= 38.7

    zero_acc_kernel<<<1, 128, 0, stream>>>(acc);

    // pre-split operands (bitwise-identical to inline split)
    split_kernel<<<dim3(NTOK * 1024 / 1024), 256, 0, stream>>>(x, xh, xl, NTOK * 1024);
    split_kernel<<<dim3(3072 * 1024 / 1024), 256, 0, stream>>>(in_w, iwh, iwl, 3072 * 1024);
    split_kernel<<<dim3(1024 * 1024 / 1024), 256, 0, stream>>>(out_w, owh, owl, 1024 * 1024);

    // QKV = x @ in_proj_w^T + b  -> hi/lo; Q cols pre-scaled 1/8
    // flat grid 24*32 = 768; each XCD owns 3 n-blocks (B-slice 1.6 MB in L2)
    gemm_ps<0, 1, 3><<<dim3(24 * 32), 256, 0, stream>>>(
        xh, xl, iwh, iwl, in_b, nullptr, qkvh, qkvl, nullptr,
        NTOK, 3072, 1024, 1024, 0.125f);

    attn_split<<<dim3(512), 256, 0, stream>>>(qkvh, qkvl, oh, ol);

    // y = o @ out_proj_w^T + b + x  -> f32; each XCD owns 1 n-block
    gemm_ps<2, 0, 1><<<dim3(8 * 32), 256, 0, stream>>>(
        oh, ol, owh, owl, out_b, x, nullptr, nullptr, ybuf,
        NTOK, 1024, 1024, 0, 1.0f);

    rmsnorm_kernel<<<NTOK, 256, 0, stream>>>(ybuf, rg, moe);
    gating_kernel<<<NTOK / 4, 256, 0, stream>>>(moe, gw, runif, tokpack, tokg, acc);
    scan_kernel<<<dim3(BSZ), 512, 0, stream>>>(tokpack, r0, r1, prev);
    gather_ln_kernel<<<NTOK, 256, 0, stream>>>(moe, r0, r1, prev, lng, lnb, eln);

    // h = LeakyReLU(LN @ w1^T + b1) -> bf16; e = id&15 (XCD-pinned per expert)
    gemm_ffn<1, 1><<<dim3(43 * 16), 256, 0, stream>>>(
        eln, w1, b1, hbuf, HFF_R, HFF_P, 1024, 1024,
        (long)320 * 1024, (long)HFF_R * 1024, HFF_R, (long)320 * HFF_P, HFF_P);

    // expert_out = h @ w2^T + b2 -> f32
    gemm_ffn<0, 0><<<dim3(16 * 16), 256, 0, stream>>>(
        hbuf, w2, b2, eoutv, 1024, 1024, HFF_P, HFF_R,
        (long)320 * HFF_P, (long)1024 * HFF_R, 1024, (long)320 * 1024, 1024);

    combine_kernel<<<NTOK, 256, 0, stream>>>(ybuf, eoutv, r0, r1, tokg, prev, out);
    finalize_kernel<<<1, 64, 0, stream>>>(acc, out + (size_t)NTOK * 1024);
}